// Round 3
// baseline (938.365 us; speedup 1.0000x reference)
//
#include <hip/hip_runtime.h>
#include <hip/hip_bf16.h>
#include <math.h>

#define B_    64
#define T_    256
#define EMB_  300
#define HW_   128
#define G4_   512     // 4*HW
#define HP_   8
#define P1_   46
#define NPOS  (B_*T_) // 16384

typedef short  short8 __attribute__((ext_vector_type(8)));
typedef float  f32x4  __attribute__((ext_vector_type(4)));

__device__ __forceinline__ float sigmoidf_(float x) {
  return 1.0f / (1.0f + __expf(-x));
}
__device__ __forceinline__ float ftanh_(float x) {
  float e = __expf(2.0f * x);
  return 1.0f - 2.0f / (e + 1.0f);
}
__device__ __forceinline__ unsigned short f2bf(float x) {   // RNE fp32->bf16
  unsigned u = __float_as_uint(x);
  u += 0x7fffu + ((u >> 16) & 1u);
  return (unsigned short)(u >> 16);
}

// ---------------------------------------------------------------------------
// Kernel 1: xg2 = gather(emb, words) @ [WiF;WiB]^T + bias
// stored as xg2[((dir*256 + t)*64 + b)*512 + c]  (c = gate-major col 0..511)
// ---------------------------------------------------------------------------
__global__ __launch_bounds__(256) void xg_gemm_k(
    const int* __restrict__ words, const float* __restrict__ emb,
    const float* __restrict__ WiF, const float* __restrict__ WiB,
    const float* __restrict__ bF,  const float* __restrict__ bB,
    float* __restrict__ xg2) {
  __shared__ float As[16][68];
  __shared__ float Ws[16][68];
  const int m0 = blockIdx.x * 64;
  const int n0 = blockIdx.y * 64;
  const int tid = threadIdx.x;
  const int tx = tid & 15, ty = tid >> 4;
  const int lm = tid >> 2, lk4 = (tid & 3) << 2;

  const int word = words[m0 + lm];
  const float* __restrict__ arow = emb + (long)word * EMB_;
  const int nrow = n0 + lm;
  const float* __restrict__ wrow = (nrow < G4_) ? (WiF + (long)nrow * EMB_)
                                                : (WiB + (long)(nrow - G4_) * EMB_);
  float acc[4][4] = {};
  for (int k0 = 0; k0 < EMB_; k0 += 16) {
    const int k = k0 + lk4;
    float4 av = make_float4(0.f,0.f,0.f,0.f);
    float4 wv = make_float4(0.f,0.f,0.f,0.f);
    if (k < EMB_) {
      av = *(const float4*)(arow + k);
      wv = *(const float4*)(wrow + k);
    }
    __syncthreads();
    As[lk4+0][lm] = av.x; As[lk4+1][lm] = av.y; As[lk4+2][lm] = av.z; As[lk4+3][lm] = av.w;
    Ws[lk4+0][lm] = wv.x; Ws[lk4+1][lm] = wv.y; Ws[lk4+2][lm] = wv.z; Ws[lk4+3][lm] = wv.w;
    __syncthreads();
    #pragma unroll
    for (int kk = 0; kk < 16; ++kk) {
      const float4 a4 = *(const float4*)&As[kk][ty << 2];
      const float4 w4 = *(const float4*)&Ws[kk][tx << 2];
      const float a[4] = {a4.x, a4.y, a4.z, a4.w};
      const float w[4] = {w4.x, w4.y, w4.z, w4.w};
      #pragma unroll
      for (int i = 0; i < 4; ++i)
        #pragma unroll
        for (int j = 0; j < 4; ++j)
          acc[i][j] += a[i] * w[j];
    }
  }
  const int n = n0 + (tx << 2);
  const int dir = n >> 9, c = n & 511;
  const float* __restrict__ bb = (n < G4_) ? (bF + n) : (bB + n - G4_);
  #pragma unroll
  for (int i = 0; i < 4; ++i) {
    const int m = m0 + (ty << 2) + i;          // global row = b*T + t
    const int b = m >> 8, t = m & 255;
    float4 o;
    o.x = acc[i][0] + bb[0];
    o.y = acc[i][1] + bb[1];
    o.z = acc[i][2] + bb[2];
    o.w = acc[i][3] + bb[3];
    *(float4*)&xg2[(long)(((dir*256 + t)*64) + b) * 512 + c] = o;
  }
}

// ---------------------------------------------------------------------------
// Kernel 2: word LSTM via MFMA. 8 blocks = (bgroup 0..3, dir 0..1), 512 thr.
// Per step: H[16][128](bf16) @ Wh^T -> G[16][512] via 16x16x32 MFMA.
// Wave w (0..7) owns gate cols [w*64,(w+1)*64): gate gx=w>>1 (uniform act).
// LDS: h_lds (bf16 A-frags, XOR-swizzled), act (fp32, XOR-swizzled).
// ---------------------------------------------------------------------------
__global__ __launch_bounds__(512) void word_lstm_mfma(
    const float* __restrict__ xg2, const float* __restrict__ WhF,
    const float* __restrict__ WhB, float* __restrict__ wo) {
  const int dir = blockIdx.x & 1;
  const int bs  = (blockIdx.x >> 1) * 16;
  const int tid = threadIdx.x;
  const int w    = tid >> 6;
  const int lane = tid & 63;
  const int lm   = lane & 15;        // m (A row / D col-index pattern)
  const int lg   = lane >> 4;        // K-group / m-slot
  const float* __restrict__ Wh = dir ? WhB : WhF;

  __shared__ char  h_bytes[16 * 256];        // 16 rows x 128 bf16 (swizzled)
  __shared__ float act_f[2048 * 4];          // 2048 16B-slots (swizzled)

  // ---- load Wh as bf16 B-frags: bfr[nt][kf], n = w*64+nt*16+lm, k = kf*32+lg*8+e
  short8 bfr[4][4];
  #pragma unroll
  for (int nt = 0; nt < 4; ++nt) {
    const int n = w * 64 + nt * 16 + lm;
    #pragma unroll
    for (int kf = 0; kf < 4; ++kf) {
      const float* p = Wh + (long)n * 128 + kf * 32 + lg * 8;
      const float4 f0 = *(const float4*)p;
      const float4 f1 = *(const float4*)(p + 4);
      union { unsigned short u[8]; short8 v; } t;
      t.u[0]=f2bf(f0.x); t.u[1]=f2bf(f0.y); t.u[2]=f2bf(f0.z); t.u[3]=f2bf(f0.w);
      t.u[4]=f2bf(f1.x); t.u[5]=f2bf(f1.y); t.u[6]=f2bf(f1.z); t.u[7]=f2bf(f1.w);
      bfr[nt][kf] = t.v;
    }
  }

  // ---- zero h_lds (h0 = 0)
  if (tid < 512) ((int2*)h_bytes)[tid] = make_int2(0, 0);

  // ---- c/h-phase identity: q = tid>>2 (0..127), mset = tid&3 (m = mset*4+j)
  const int q_ch  = tid >> 2;
  const int mset  = tid & 3;
  float cst[4] = {0.f, 0.f, 0.f, 0.f};

  // ---- xg prefetch (MFMA-role mapping): xgc[nt*4+r]
  float xgc[16];
  {
    const int t0 = dir ? (T_ - 1) : 0;
    const long base = ((long)(dir * 256 + t0) * 64 + bs) * 512;
    #pragma unroll
    for (int nt = 0; nt < 4; ++nt)
      #pragma unroll
      for (int r = 0; r < 4; ++r) {
        const int m = lg * 4 + r;
        const int col = w * 64 + nt * 16 + lm;
        xgc[nt * 4 + r] = xg2[base + (long)m * 512 + col];
      }
  }
  __syncthreads();

  for (int s = 0; s < T_; ++s) {
    const int t = dir ? (T_ - 1 - s) : s;
    // (A) A-frags from h_lds (swizzled b128 reads) + MFMA
    short8 af[4];
    #pragma unroll
    for (int kf = 0; kf < 4; ++kf) {
      const int slot = (kf * 4 + lg) ^ (lm & 7);
      af[kf] = *(const short8*)(h_bytes + lm * 256 + (slot << 4));
    }
    f32x4 acc[4];
    #pragma unroll
    for (int nt = 0; nt < 4; ++nt) {
      f32x4 a = {0.f, 0.f, 0.f, 0.f};
      #pragma unroll
      for (int kf = 0; kf < 4; ++kf)
        a = __builtin_amdgcn_mfma_f32_16x16x32_bf16(af[kf], bfr[nt][kf], a, 0, 0, 0);
      acc[nt] = a;
    }
    // (B) += xg, activation (gate-uniform per wave), write act to LDS
    const int gx = w >> 1;
    #pragma unroll
    for (int nt = 0; nt < 4; ++nt) {
      const int q = (w & 1) * 64 + nt * 16 + lm;
      f32x4 tv;
      #pragma unroll
      for (int r = 0; r < 4; ++r) {
        const float v = acc[nt][r] + xgc[nt * 4 + r];
        tv[r] = (gx == 2) ? ftanh_(v) : sigmoidf_(v);
      }
      const int slot = ((q * 4 + gx) * 4 + lg) ^ (q & 7);
      *(f32x4*)(act_f + (slot << 2)) = tv;
    }
    __syncthreads();
    // (D) c/h update (thread owns (q_ch, m = mset*4+j))
    f32x4 gate[4];
    #pragma unroll
    for (int gxx = 0; gxx < 4; ++gxx) {
      const int slot = ((q_ch * 4 + gxx) * 4 + mset) ^ (q_ch & 7);
      gate[gxx] = *(const f32x4*)(act_f + (slot << 2));
    }
    #pragma unroll
    for (int j = 0; j < 4; ++j) {
      const int m = mset * 4 + j;
      const float ig = gate[0][j], fg = gate[1][j], gg = gate[2][j], og = gate[3][j];
      cst[j] = fg * cst[j] + ig * gg;
      const float h = og * ftanh_(cst[j]);
      // global wo
      wo[((long)(bs + m) * T_ + t) * 256 + dir * 128 + q_ch] = h;
      // h_lds (bf16, swizzled)
      const int slot = (q_ch >> 3) ^ (m & 7);
      *(unsigned short*)(h_bytes + m * 256 + (slot << 4) + ((q_ch & 7) * 2)) = f2bf(h);
    }
    // prefetch next step's xg (MFMA-role mapping)
    if (s + 1 < T_) {
      const int tn = dir ? (T_ - 2 - s) : (s + 1);
      const long base = ((long)(dir * 256 + tn) * 64 + bs) * 512;
      #pragma unroll
      for (int nt = 0; nt < 4; ++nt)
        #pragma unroll
        for (int r = 0; r < 4; ++r) {
          const int m = lg * 4 + r;
          const int col = w * 64 + nt * 16 + lm;
          xgc[nt * 4 + r] = xg2[base + (long)m * 512 + col];
        }
    }
    __syncthreads();
  }
}

// ---------------------------------------------------------------------------
// Kernel 3: pos LSTM (input one-hot -> gather column of Wi). 128 blocks x 64.
// ---------------------------------------------------------------------------
__global__ __launch_bounds__(64) void pos_lstm_k(
    const int* __restrict__ pos,
    const float* __restrict__ WiF, const float* __restrict__ WhF, const float* __restrict__ bF,
    const float* __restrict__ WiB, const float* __restrict__ WhB, const float* __restrict__ bB,
    float* __restrict__ po) {
  const int blk = blockIdx.x;
  const int b   = blk & 63;
  const int dir = blk >> 6;
  const float* __restrict__ Wi = dir ? WiB : WiF;   // [32][46]
  const float* __restrict__ Wh = dir ? WhB : WhF;   // [32][8]
  const float* __restrict__ bias = dir ? bB : bF;

  __shared__ float Wis[32 * P1_];
  const int lane = threadIdx.x;
  for (int i = lane; i < 32 * P1_; i += 64) Wis[i] = Wi[i];
  __syncthreads();

  float w[8] = {};
  float bi = 0.f;
  if (lane < 32) {
    #pragma unroll
    for (int j = 0; j < 8; ++j) w[j] = Wh[lane * 8 + j];
    bi = bias[lane];
  }
  float h[8] = {};
  float cc = 0.f;
  for (int s = 0; s < T_; ++s) {
    const int tt = dir ? (T_ - 1 - s) : s;
    const int p = pos[b * T_ + tt];
    float acc = 0.f;
    if (lane < 32) {
      acc = Wis[lane * P1_ + p] + bi;
      #pragma unroll
      for (int j = 0; j < 8; ++j) acc += w[j] * h[j];
    }
    const float act = (lane >= 16 && lane < 24) ? ftanh_(acc) : sigmoidf_(acc);
    const float a_f = __shfl_down(act, 8);
    const float a_g = __shfl_down(act, 16);
    const float a_o = __shfl_down(act, 24);
    float hnew = 0.f;
    if (lane < 8) {
      cc = a_f * cc + act * a_g;
      hnew = a_o * ftanh_(cc);
      po[(long)(b * T_ + tt) * 16 + dir * 8 + lane] = hnew;
    }
    #pragma unroll
    for (int j = 0; j < 8; ++j) h[j] = __shfl(hnew, j);
  }
}

// ---------------------------------------------------------------------------
// Kernel 4: wh = relu(wo[16384,256] @ whW^T[256,128] + whb)
// ---------------------------------------------------------------------------
__global__ __launch_bounds__(256) void wh_gemm_k(
    const float* __restrict__ A, const float* __restrict__ W,
    const float* __restrict__ bias, float* __restrict__ out) {
  __shared__ float As[16][68];
  __shared__ float Ws[16][68];
  const int m0 = blockIdx.x * 64;
  const int n0 = blockIdx.y * 64;
  const int tid = threadIdx.x;
  const int tx = tid & 15, ty = tid >> 4;
  const int lm = tid >> 2, lk4 = (tid & 3) << 2;
  const float* __restrict__ arow = A + (long)(m0 + lm) * 256;
  const float* __restrict__ wrow = W + (long)(n0 + lm) * 256;
  float acc[4][4] = {};
  for (int k0 = 0; k0 < 256; k0 += 16) {
    const int k = k0 + lk4;
    const float4 av = *(const float4*)(arow + k);
    const float4 wv = *(const float4*)(wrow + k);
    __syncthreads();
    As[lk4+0][lm] = av.x; As[lk4+1][lm] = av.y; As[lk4+2][lm] = av.z; As[lk4+3][lm] = av.w;
    Ws[lk4+0][lm] = wv.x; Ws[lk4+1][lm] = wv.y; Ws[lk4+2][lm] = wv.z; Ws[lk4+3][lm] = wv.w;
    __syncthreads();
    #pragma unroll
    for (int kk = 0; kk < 16; ++kk) {
      const float4 a4 = *(const float4*)&As[kk][ty << 2];
      const float4 w4 = *(const float4*)&Ws[kk][tx << 2];
      const float a[4] = {a4.x, a4.y, a4.z, a4.w};
      const float w[4] = {w4.x, w4.y, w4.z, w4.w};
      #pragma unroll
      for (int i = 0; i < 4; ++i)
        #pragma unroll
        for (int j = 0; j < 4; ++j)
          acc[i][j] += a[i] * w[j];
    }
  }
  const int n = n0 + (tx << 2);
  #pragma unroll
  for (int i = 0; i < 4; ++i) {
    const int m = m0 + (ty << 2) + i;
    float4 o;
    o.x = fmaxf(acc[i][0] + bias[n+0], 0.f);
    o.y = fmaxf(acc[i][1] + bias[n+1], 0.f);
    o.z = fmaxf(acc[i][2] + bias[n+2], 0.f);
    o.w = fmaxf(acc[i][3] + bias[n+3], 0.f);
    *(float4*)&out[(long)m * 128 + n] = o;
  }
}

// ---------------------------------------------------------------------------
// Kernel 5: ph = relu(po@phW^T+phb); feats = relu([wh,ph]@tagW^T + tagb)
// ---------------------------------------------------------------------------
__global__ __launch_bounds__(256) void feats_k(
    const float* __restrict__ wh, const float* __restrict__ po,
    const float* __restrict__ phW, const float* __restrict__ phb,
    const float* __restrict__ tagW, const float* __restrict__ tagb,
    float* __restrict__ feats) {
  __shared__ float phWs[8 * 16], phbs[8], tagWs[6 * 136], tagbs[6];
  const int tid = threadIdx.x;
  for (int i = tid; i < 128; i += 256) phWs[i] = phW[i];
  if (tid < 8) phbs[tid] = phb[tid];
  for (int i = tid; i < 816; i += 256) tagWs[i] = tagW[i];
  if (tid < 6) tagbs[tid] = tagb[tid];
  __syncthreads();
  const int posi = blockIdx.x * 256 + tid;
  const float* __restrict__ por = po + (long)posi * 16;
  float pv[16];
  #pragma unroll
  for (int i = 0; i < 16; i += 4) {
    const float4 v = *(const float4*)(por + i);
    pv[i] = v.x; pv[i+1] = v.y; pv[i+2] = v.z; pv[i+3] = v.w;
  }
  float ph[8];
  #pragma unroll
  for (int o = 0; o < 8; ++o) {
    float a = phbs[o];
    #pragma unroll
    for (int k = 0; k < 16; ++k) a += pv[k] * phWs[o * 16 + k];
    ph[o] = fmaxf(a, 0.f);
  }
  float f[6];
  #pragma unroll
  for (int o = 0; o < 6; ++o) f[o] = tagbs[o];
  const float* __restrict__ whr = wh + (long)posi * 128;
  for (int k = 0; k < 128; k += 4) {
    const float4 v = *(const float4*)(whr + k);
    #pragma unroll
    for (int o = 0; o < 6; ++o)
      f[o] += v.x * tagWs[o*136 + k] + v.y * tagWs[o*136 + k+1]
            + v.z * tagWs[o*136 + k+2] + v.w * tagWs[o*136 + k+3];
  }
  #pragma unroll
  for (int o = 0; o < 6; ++o) {
    #pragma unroll
    for (int k = 0; k < 8; ++k) f[o] += ph[k] * tagWs[o*136 + 128 + k];
    feats[(long)posi * 6 + o] = fmaxf(f[o], 0.f);
  }
}

// ---------------------------------------------------------------------------
// Kernel 6: CRF NLL. One block, 512 threads: 8 lanes per batch element.
// ---------------------------------------------------------------------------
__global__ __launch_bounds__(512) void crf_k(
    const int* __restrict__ words, const int* __restrict__ labels,
    const float* __restrict__ feats, const float* __restrict__ trans,
    float* __restrict__ out) {
  __shared__ float tn_s[36];
  __shared__ float tE_s[6];
  __shared__ float res_s[64];
  const int tid = threadIdx.x;
  if (tid < 36) {
    const int nx = tid / 6, pv = tid % 6;
    float mx = -1e30f;
    for (int q = 0; q < 6; ++q) mx = fmaxf(mx, trans[q * 6 + pv]);
    float s = 0.f;
    for (int q = 0; q < 6; ++q) s += __expf(trans[q * 6 + pv] - mx);
    tn_s[tid] = (pv == 4) ? -100.f : (__expf(trans[nx * 6 + pv] - mx) / s);
  }
  if (tid < 6) tE_s[tid] = trans[4 * 6 + tid];   // raw END row
  __syncthreads();

  const int lane = tid & 63;
  const int wv   = tid >> 6;
  const int sub  = lane & 7;
  const int b    = wv * 8 + (lane >> 3);

  int cnt = 0;
  for (int t = sub; t < T_; t += 8) cnt += (words[b * T_ + t] != 0) ? 1 : 0;
  cnt += __shfl_xor(cnt, 1); cnt += __shfl_xor(cnt, 2); cnt += __shfl_xor(cnt, 4);
  const int len = cnt;

  float tnr[6];
  #pragma unroll
  for (int p = 0; p < 6; ++p) tnr[p] = (sub < 6) ? tn_s[sub * 6 + p] : -100.f;
  float alpha = (sub == 3) ? 0.f : -100.f;   // START=3
  for (int t = 0; t < T_; ++t) {
    float ap[6];
    #pragma unroll
    for (int p = 0; p < 6; ++p) ap[p] = __shfl(alpha, p, 8) + tnr[p];
    const float feat = (sub < 6) ? feats[(long)(b * T_ + t) * 6 + sub] : 0.f;
    float m = ap[0];
    #pragma unroll
    for (int p = 1; p < 6; ++p) m = fmaxf(m, ap[p]);
    float s = 0.f;
    #pragma unroll
    for (int p = 0; p < 6; ++p) s += __expf(ap[p] - m);
    const float anew = m + __logf(s) + feat;
    alpha = (t < len) ? anew : alpha;
  }
  float v = (sub < 6) ? (alpha + tE_s[sub]) : -1e30f;
  float m2 = v;
  m2 = fmaxf(m2, __shfl_xor(m2, 1));
  m2 = fmaxf(m2, __shfl_xor(m2, 2));
  m2 = fmaxf(m2, __shfl_xor(m2, 4));
  float e = (sub < 6) ? __expf(v - m2) : 0.f;
  e += __shfl_xor(e, 1); e += __shfl_xor(e, 2); e += __shfl_xor(e, 4);
  const float fwd = m2 + __logf(e);

  int fp = T_;
  for (int t = sub; t < T_; t += 8)
    if (labels[b * T_ + t] == 5) fp = min(fp, t);
  fp = min(fp, __shfl_xor(fp, 1));
  fp = min(fp, __shfl_xor(fp, 2));
  fp = min(fp, __shfl_xor(fp, 4));
  float gs = 0.f;
  for (int t = sub; t < T_; t += 8) {
    if (t < fp) {
      const int lab = labels[b * T_ + t];
      const int prv = (t == 0) ? 3 : labels[b * T_ + t - 1];
      gs += feats[(long)(b * T_ + t) * 6 + lab] + tn_s[lab * 6 + prv];
    }
  }
  gs += __shfl_xor(gs, 1); gs += __shfl_xor(gs, 2); gs += __shfl_xor(gs, 4);
  const float gold = gs + trans[4 * 6 + labels[b * T_ + T_ - 1]];
  if (sub == 0) res_s[b] = fwd - gold;
  __syncthreads();
  if (tid == 0) {
    float r = 0.f;
    for (int i = 0; i < 64; ++i) r += res_s[i];
    out[0] = r * (1.0f / 64.0f);
  }
}

// ---------------------------------------------------------------------------
extern "C" void kernel_launch(void* const* d_in, const int* in_sizes, int n_in,
                              void* d_out, int out_size, void* d_ws, size_t ws_size,
                              hipStream_t stream) {
  (void)in_sizes; (void)n_in; (void)out_size; (void)ws_size;
  const int*   words = (const int*)d_in[0];
  const int*   postg = (const int*)d_in[1];
  const int*   labels= (const int*)d_in[2];
  const float* emb_w = (const float*)d_in[3];
  const float* wlfWi = (const float*)d_in[5];
  const float* wlfWh = (const float*)d_in[6];
  const float* wlfb  = (const float*)d_in[7];
  const float* wlbWi = (const float*)d_in[8];
  const float* wlbWh = (const float*)d_in[9];
  const float* wlbb  = (const float*)d_in[10];
  const float* plfWi = (const float*)d_in[11];
  const float* plfWh = (const float*)d_in[12];
  const float* plfb  = (const float*)d_in[13];
  const float* plbWi = (const float*)d_in[14];
  const float* plbWh = (const float*)d_in[15];
  const float* plbb  = (const float*)d_in[16];
  const float* whW   = (const float*)d_in[17];
  const float* whb   = (const float*)d_in[18];
  const float* phW   = (const float*)d_in[19];
  const float* phb   = (const float*)d_in[20];
  const float* tagW  = (const float*)d_in[21];
  const float* tagb  = (const float*)d_in[22];
  const float* trans = (const float*)d_in[23];

  float* ws = (float*)d_ws;
  float* xg = ws;                          // [2][256][64][512]
  float* wo = xg + (size_t)NPOS * 1024;    // [16384][256]
  float* po = wo + (size_t)NPOS * 256;     // [16384][16]
  float* wh = po + (size_t)NPOS * 16;      // [16384][128]
  float* fe = wh + (size_t)NPOS * 128;     // [16384][6]

  hipLaunchKernelGGL(xg_gemm_k, dim3(NPOS / 64, 1024 / 64), dim3(256), 0, stream,
                     words, emb_w, wlfWi, wlbWi, wlfb, wlbb, xg);
  hipLaunchKernelGGL(word_lstm_mfma, dim3(8), dim3(512), 0, stream,
                     xg, wlfWh, wlbWh, wo);
  hipLaunchKernelGGL(pos_lstm_k, dim3(128), dim3(64), 0, stream,
                     postg, plfWi, plfWh, plfb, plbWi, plbWh, plbb, po);
  hipLaunchKernelGGL(wh_gemm_k, dim3(NPOS / 64, 128 / 64), dim3(256), 0, stream,
                     wo, whW, whb, wh);
  hipLaunchKernelGGL(feats_k, dim3(NPOS / 256), dim3(256), 0, stream,
                     wh, po, phW, phb, tagW, tagb, fe);
  hipLaunchKernelGGL(crf_k, dim3(1), dim3(512), 0, stream,
                     words, labels, fe, trans, (float*)d_out);
}

// Round 4
// 551.901 us; speedup vs baseline: 1.7002x; 1.7002x over previous
//
#include <hip/hip_runtime.h>
#include <hip/hip_bf16.h>
#include <math.h>

#define B_    64
#define T_    256
#define EMB_  300
#define HW_   128
#define G4_   512     // 4*HW
#define P1_   46
#define NPOS  (B_*T_) // 16384

typedef short  short8 __attribute__((ext_vector_type(8)));
typedef float  f32x4  __attribute__((ext_vector_type(4)));

__device__ __forceinline__ float sigmoidf_(float x) {
  return 1.0f / (1.0f + __expf(-x));
}
__device__ __forceinline__ float ftanh_(float x) {
  float e = __expf(2.0f * x);
  return 1.0f - 2.0f / (e + 1.0f);
}
__device__ __forceinline__ unsigned short f2bf(float x) {   // RNE fp32->bf16
  unsigned u = __float_as_uint(x);
  u += 0x7fffu + ((u >> 16) & 1u);
  return (unsigned short)(u >> 16);
}
template<int CTRL>
__device__ __forceinline__ float qb(float v) {   // quad_perm broadcast (DPP, VALU)
  return __int_as_float(__builtin_amdgcn_mov_dpp(__float_as_int(v), CTRL, 0xf, 0xf, true));
}

// ---------------------------------------------------------------------------
// Kernel 1 (merged): blocks [0,128) = pos LSTM; blocks [128,4224) = xg GEMM.
// xg2[((dir*256 + t)*64 + b)*512 + c], c = gate-major col (g*128+q).
// ---------------------------------------------------------------------------
__global__ __launch_bounds__(256) void front_k(
    const int* __restrict__ words, const float* __restrict__ emb,
    const float* __restrict__ WiF, const float* __restrict__ WiB,
    const float* __restrict__ bF,  const float* __restrict__ bB,
    float* __restrict__ xg2,
    const int* __restrict__ pos,
    const float* __restrict__ pWiF, const float* __restrict__ pWhF, const float* __restrict__ pbF,
    const float* __restrict__ pWiB, const float* __restrict__ pWhB, const float* __restrict__ pbB,
    float* __restrict__ po) {
  const int tid = threadIdx.x;
  if (blockIdx.x < 128) {
    // ---------------- pos LSTM (serial, 1 wave active) ----------------
    const int blk = blockIdx.x;
    const int b   = blk & 63;
    const int dir = blk >> 6;
    const float* __restrict__ Wi = dir ? pWiB : pWiF;   // [32][46]
    const float* __restrict__ Wh = dir ? pWhB : pWhF;   // [32][8]
    const float* __restrict__ bias = dir ? pbB : pbF;
    __shared__ float Wis[32 * P1_];
    for (int i = tid; i < 32 * P1_; i += 256) Wis[i] = Wi[i];
    __syncthreads();
    if (tid >= 64) return;
    const int lane = tid;
    float w[8] = {};
    float bi = 0.f;
    if (lane < 32) {
      #pragma unroll
      for (int j = 0; j < 8; ++j) w[j] = Wh[lane * 8 + j];
      bi = bias[lane];
    }
    float h[8] = {};
    float cc = 0.f;
    for (int s = 0; s < T_; ++s) {
      const int tt = dir ? (T_ - 1 - s) : s;
      const int p = pos[b * T_ + tt];
      float acc = 0.f;
      if (lane < 32) {
        acc = Wis[lane * P1_ + p] + bi;
        #pragma unroll
        for (int j = 0; j < 8; ++j) acc += w[j] * h[j];
      }
      const float act = (lane >= 16 && lane < 24) ? ftanh_(acc) : sigmoidf_(acc);
      const float a_f = __shfl_down(act, 8);
      const float a_g = __shfl_down(act, 16);
      const float a_o = __shfl_down(act, 24);
      float hnew = 0.f;
      if (lane < 8) {
        cc = a_f * cc + act * a_g;
        hnew = a_o * ftanh_(cc);
        po[(long)(b * T_ + tt) * 16 + dir * 8 + lane] = hnew;
      }
      #pragma unroll
      for (int j = 0; j < 8; ++j) h[j] = __shfl(hnew, j);
    }
    return;
  }
  // ---------------- xg GEMM ----------------
  __shared__ float As[16][68];
  __shared__ float Ws[16][68];
  const int xb = blockIdx.x - 128;
  const int m0 = (xb & 255) * 64;
  const int n0 = (xb >> 8) * 64;
  const int tx = tid & 15, ty = tid >> 4;
  const int lm = tid >> 2, lk4 = (tid & 3) << 2;

  const int word = words[m0 + lm];
  const float* __restrict__ arow = emb + (long)word * EMB_;
  const int nrow = n0 + lm;
  const float* __restrict__ wrow = (nrow < G4_) ? (WiF + (long)nrow * EMB_)
                                                : (WiB + (long)(nrow - G4_) * EMB_);
  float acc[4][4] = {};
  for (int k0 = 0; k0 < EMB_; k0 += 16) {
    const int k = k0 + lk4;
    float4 av = make_float4(0.f,0.f,0.f,0.f);
    float4 wv = make_float4(0.f,0.f,0.f,0.f);
    if (k < EMB_) {
      av = *(const float4*)(arow + k);
      wv = *(const float4*)(wrow + k);
    }
    __syncthreads();
    As[lk4+0][lm] = av.x; As[lk4+1][lm] = av.y; As[lk4+2][lm] = av.z; As[lk4+3][lm] = av.w;
    Ws[lk4+0][lm] = wv.x; Ws[lk4+1][lm] = wv.y; Ws[lk4+2][lm] = wv.z; Ws[lk4+3][lm] = wv.w;
    __syncthreads();
    #pragma unroll
    for (int kk = 0; kk < 16; ++kk) {
      const float4 a4 = *(const float4*)&As[kk][ty << 2];
      const float4 w4 = *(const float4*)&Ws[kk][tx << 2];
      const float a[4] = {a4.x, a4.y, a4.z, a4.w};
      const float w[4] = {w4.x, w4.y, w4.z, w4.w};
      #pragma unroll
      for (int i = 0; i < 4; ++i)
        #pragma unroll
        for (int j = 0; j < 4; ++j)
          acc[i][j] += a[i] * w[j];
    }
  }
  const int n = n0 + (tx << 2);
  const int dir = n >> 9, c = n & 511;
  const float* __restrict__ bb = (n < G4_) ? (bF + n) : (bB + n - G4_);
  #pragma unroll
  for (int i = 0; i < 4; ++i) {
    const int m = m0 + (ty << 2) + i;          // global row = b*T + t
    const int b = m >> 8, t = m & 255;
    float4 o;
    o.x = acc[i][0] + bb[0];
    o.y = acc[i][1] + bb[1];
    o.z = acc[i][2] + bb[2];
    o.w = acc[i][3] + bb[3];
    *(float4*)&xg2[(long)(((dir*256 + t)*64) + b) * 512 + c] = o;
  }
}

// ---------------------------------------------------------------------------
// Kernel 2: word LSTM, M=1 MFMA, 128 blocks = (b,dir), 512 threads (8 waves).
// Wave w owns q in [w*16,(w+1)*16). Col n = (q&3... ) mapping:
//   B-frag col n (lane&15): q = w*16 + nt*4 + (n>>2), gate g = n&3.
// A-frag: h bf16 broadcast from 256B LDS (uniform addr per 16-lane group) -->
//   every lane's D reg0 = G[its col]. Gate exchange via DPP quad_perm.
// One barrier/step (double-buffered h). xg prefetched 2 steps ahead.
// ---------------------------------------------------------------------------
__global__ __launch_bounds__(512) void word_lstm_mfma2(
    const float* __restrict__ xg2, const float* __restrict__ WhF,
    const float* __restrict__ WhB, float* __restrict__ wo) {
  const int b    = blockIdx.x >> 1;
  const int dir  = blockIdx.x & 1;
  const int tid  = threadIdx.x;
  const int w    = tid >> 6;
  const int lane = tid & 63;
  const int l15  = lane & 15;
  const int lg   = lane >> 4;      // k-group 0..3
  const int g    = lane & 3;       // gate of this col
  const int qloc = l15 >> 2;       // 0..3
  const float* __restrict__ Wh = dir ? WhB : WhF;

  // B-frags: bfr[nt][kf]; col n=l15 -> row r = g*128 + q, k = kf*32 + lg*8 + e
  short8 bfr[4][4];
  #pragma unroll
  for (int nt = 0; nt < 4; ++nt) {
    const int q = w * 16 + nt * 4 + qloc;
    const int r = g * 128 + q;
    #pragma unroll
    for (int kf = 0; kf < 4; ++kf) {
      const float* p = Wh + (long)r * 128 + kf * 32 + lg * 8;
      const float4 f0 = *(const float4*)p;
      const float4 f1 = *(const float4*)(p + 4);
      union { unsigned short u[8]; short8 v; } t;
      t.u[0]=f2bf(f0.x); t.u[1]=f2bf(f0.y); t.u[2]=f2bf(f0.z); t.u[3]=f2bf(f0.w);
      t.u[4]=f2bf(f1.x); t.u[5]=f2bf(f1.y); t.u[6]=f2bf(f1.z); t.u[7]=f2bf(f1.w);
      bfr[nt][kf] = t.v;
    }
  }

  __shared__ __align__(16) unsigned short h2[2][128];   // bf16 h, double buffer
  if (tid < 128) { h2[0][tid] = 0; h2[1][tid] = 0; }

  float cst[4] = {0.f, 0.f, 0.f, 0.f};
  // divergence-free activation constants: g==2 -> tanh(x) = 2*sigmoid(2x)-1
  const float kmul = (g == 2) ? 2.f : 1.f;
  const float amul = (g == 2) ? 2.f : 1.f;
  const float aadd = (g == 2) ? -1.f : 0.f;

  // xg addressing: xg2[((dir*256+t)*64+b)*512 + g*128 + w*16 + nt*4 + qloc]
  const float* __restrict__ xq =
      xg2 + (long)(dir * 256) * 32768 + (long)b * 512 + (g * 128 + w * 16 + qloc);
  float xq0[4], xq1[4];
  {
    const int t0 = dir ? 255 : 0;
    const int t1 = dir ? 254 : 1;
    #pragma unroll
    for (int nt = 0; nt < 4; ++nt) {
      xq0[nt] = xq[(long)t0 * 32768 + nt * 4];
      xq1[nt] = xq[(long)t1 * 32768 + nt * 4];
    }
  }
  __syncthreads();

  for (int s = 0; s < T_; ++s) {
    const int t = dir ? (255 - s) : s;
    // prefetch t+2
    float xq2v[4] = {0.f, 0.f, 0.f, 0.f};
    if (s + 2 < T_) {
      const int tn = dir ? (253 - s) : (s + 2);
      #pragma unroll
      for (int nt = 0; nt < 4; ++nt) xq2v[nt] = xq[(long)tn * 32768 + nt * 4];
    }
    // A-frags: broadcast reads of h (uniform addr within 16-lane group)
    const unsigned short* hb = h2[s & 1];
    short8 af[4];
    #pragma unroll
    for (int kf = 0; kf < 4; ++kf)
      af[kf] = *(const short8*)(hb + kf * 32 + lg * 8);
    f32x4 acc[4];
    #pragma unroll
    for (int nt = 0; nt < 4; ++nt) {
      f32x4 a = {0.f, 0.f, 0.f, 0.f};
      #pragma unroll
      for (int kf = 0; kf < 4; ++kf)
        a = __builtin_amdgcn_mfma_f32_16x16x32_bf16(af[kf], bfr[nt][kf], a, 0, 0, 0);
      acc[nt] = a;
    }
    // gates + c/h (every lane has G[its col] in acc[nt][0])
    #pragma unroll
    for (int nt = 0; nt < 4; ++nt) {
      const float x  = acc[nt][0] + xq0[nt];
      const float sg = 1.0f / (1.0f + __expf(-x * kmul));
      const float act = sg * amul + aadd;
      const float vi = qb<0x00>(act);
      const float vf = qb<0x55>(act);
      const float vg = qb<0xAA>(act);
      const float vo = qb<0xFF>(act);
      cst[nt] = vf * cst[nt] + vi * vg;
      const float e2 = __expf(2.0f * cst[nt]);
      const float th = 1.0f - 2.0f / (e2 + 1.0f);
      const float hh = vo * th;
      if (lane < 16 && g == 0) {
        const int q = w * 16 + nt * 4 + qloc;
        h2[(s + 1) & 1][q] = f2bf(hh);
        wo[((long)(b * T_ + t)) * 256 + dir * 128 + q] = hh;
      }
    }
    #pragma unroll
    for (int nt = 0; nt < 4; ++nt) { xq0[nt] = xq1[nt]; xq1[nt] = xq2v[nt]; }
    __syncthreads();
  }
}

// ---------------------------------------------------------------------------
// Kernel 4: wh = relu(wo[16384,256] @ whW^T[256,128] + whb)
// ---------------------------------------------------------------------------
__global__ __launch_bounds__(256) void wh_gemm_k(
    const float* __restrict__ A, const float* __restrict__ W,
    const float* __restrict__ bias, float* __restrict__ out) {
  __shared__ float As[16][68];
  __shared__ float Ws[16][68];
  const int m0 = blockIdx.x * 64;
  const int n0 = blockIdx.y * 64;
  const int tid = threadIdx.x;
  const int tx = tid & 15, ty = tid >> 4;
  const int lm = tid >> 2, lk4 = (tid & 3) << 2;
  const float* __restrict__ arow = A + (long)(m0 + lm) * 256;
  const float* __restrict__ wrow = W + (long)(n0 + lm) * 256;
  float acc[4][4] = {};
  for (int k0 = 0; k0 < 256; k0 += 16) {
    const int k = k0 + lk4;
    const float4 av = *(const float4*)(arow + k);
    const float4 wv = *(const float4*)(wrow + k);
    __syncthreads();
    As[lk4+0][lm] = av.x; As[lk4+1][lm] = av.y; As[lk4+2][lm] = av.z; As[lk4+3][lm] = av.w;
    Ws[lk4+0][lm] = wv.x; Ws[lk4+1][lm] = wv.y; Ws[lk4+2][lm] = wv.z; Ws[lk4+3][lm] = wv.w;
    __syncthreads();
    #pragma unroll
    for (int kk = 0; kk < 16; ++kk) {
      const float4 a4 = *(const float4*)&As[kk][ty << 2];
      const float4 w4 = *(const float4*)&Ws[kk][tx << 2];
      const float a[4] = {a4.x, a4.y, a4.z, a4.w};
      const float w[4] = {w4.x, w4.y, w4.z, w4.w};
      #pragma unroll
      for (int i = 0; i < 4; ++i)
        #pragma unroll
        for (int j = 0; j < 4; ++j)
          acc[i][j] += a[i] * w[j];
    }
  }
  const int n = n0 + (tx << 2);
  #pragma unroll
  for (int i = 0; i < 4; ++i) {
    const int m = m0 + (ty << 2) + i;
    float4 o;
    o.x = fmaxf(acc[i][0] + bias[n+0], 0.f);
    o.y = fmaxf(acc[i][1] + bias[n+1], 0.f);
    o.z = fmaxf(acc[i][2] + bias[n+2], 0.f);
    o.w = fmaxf(acc[i][3] + bias[n+3], 0.f);
    *(float4*)&out[(long)m * 128 + n] = o;
  }
}

// ---------------------------------------------------------------------------
// Kernel 5: ph = relu(po@phW^T+phb); feats = relu([wh,ph]@tagW^T + tagb)
// ---------------------------------------------------------------------------
__global__ __launch_bounds__(256) void feats_k(
    const float* __restrict__ wh, const float* __restrict__ po,
    const float* __restrict__ phW, const float* __restrict__ phb,
    const float* __restrict__ tagW, const float* __restrict__ tagb,
    float* __restrict__ feats) {
  __shared__ float phWs[8 * 16], phbs[8], tagWs[6 * 136], tagbs[6];
  const int tid = threadIdx.x;
  for (int i = tid; i < 128; i += 256) phWs[i] = phW[i];
  if (tid < 8) phbs[tid] = phb[tid];
  for (int i = tid; i < 816; i += 256) tagWs[i] = tagW[i];
  if (tid < 6) tagbs[tid] = tagb[tid];
  __syncthreads();
  const int posi = blockIdx.x * 256 + tid;
  const float* __restrict__ por = po + (long)posi * 16;
  float pv[16];
  #pragma unroll
  for (int i = 0; i < 16; i += 4) {
    const float4 v = *(const float4*)(por + i);
    pv[i] = v.x; pv[i+1] = v.y; pv[i+2] = v.z; pv[i+3] = v.w;
  }
  float ph[8];
  #pragma unroll
  for (int o = 0; o < 8; ++o) {
    float a = phbs[o];
    #pragma unroll
    for (int k = 0; k < 16; ++k) a += pv[k] * phWs[o * 16 + k];
    ph[o] = fmaxf(a, 0.f);
  }
  float f[6];
  #pragma unroll
  for (int o = 0; o < 6; ++o) f[o] = tagbs[o];
  const float* __restrict__ whr = wh + (long)posi * 128;
  for (int k = 0; k < 128; k += 4) {
    const float4 v = *(const float4*)(whr + k);
    #pragma unroll
    for (int o = 0; o < 6; ++o)
      f[o] += v.x * tagWs[o*136 + k] + v.y * tagWs[o*136 + k+1]
            + v.z * tagWs[o*136 + k+2] + v.w * tagWs[o*136 + k+3];
  }
  #pragma unroll
  for (int o = 0; o < 6; ++o) {
    #pragma unroll
    for (int k = 0; k < 8; ++k) f[o] += ph[k] * tagWs[o*136 + 128 + k];
    feats[(long)posi * 6 + o] = fmaxf(f[o], 0.f);
  }
}

// ---------------------------------------------------------------------------
// Kernel 6: CRF NLL. One block, 512 threads: 8 lanes per batch element.
// ---------------------------------------------------------------------------
__global__ __launch_bounds__(512) void crf_k(
    const int* __restrict__ words, const int* __restrict__ labels,
    const float* __restrict__ feats, const float* __restrict__ trans,
    float* __restrict__ out) {
  __shared__ float tn_s[36];
  __shared__ float tE_s[6];
  __shared__ float res_s[64];
  const int tid = threadIdx.x;
  if (tid < 36) {
    const int nx = tid / 6, pv = tid % 6;
    float mx = -1e30f;
    for (int q = 0; q < 6; ++q) mx = fmaxf(mx, trans[q * 6 + pv]);
    float s = 0.f;
    for (int q = 0; q < 6; ++q) s += __expf(trans[q * 6 + pv] - mx);
    tn_s[tid] = (pv == 4) ? -100.f : (__expf(trans[nx * 6 + pv] - mx) / s);
  }
  if (tid < 6) tE_s[tid] = trans[4 * 6 + tid];   // raw END row
  __syncthreads();

  const int lane = tid & 63;
  const int wv   = tid >> 6;
  const int sub  = lane & 7;
  const int b    = wv * 8 + (lane >> 3);

  int cnt = 0;
  for (int t = sub; t < T_; t += 8) cnt += (words[b * T_ + t] != 0) ? 1 : 0;
  cnt += __shfl_xor(cnt, 1); cnt += __shfl_xor(cnt, 2); cnt += __shfl_xor(cnt, 4);
  const int len = cnt;

  float tnr[6];
  #pragma unroll
  for (int p = 0; p < 6; ++p) tnr[p] = (sub < 6) ? tn_s[sub * 6 + p] : -100.f;
  float alpha = (sub == 3) ? 0.f : -100.f;   // START=3
  for (int t = 0; t < T_; ++t) {
    float ap[6];
    #pragma unroll
    for (int p = 0; p < 6; ++p) ap[p] = __shfl(alpha, p, 8) + tnr[p];
    const float feat = (sub < 6) ? feats[(long)(b * T_ + t) * 6 + sub] : 0.f;
    float m = ap[0];
    #pragma unroll
    for (int p = 1; p < 6; ++p) m = fmaxf(m, ap[p]);
    float s = 0.f;
    #pragma unroll
    for (int p = 0; p < 6; ++p) s += __expf(ap[p] - m);
    const float anew = m + __logf(s) + feat;
    alpha = (t < len) ? anew : alpha;
  }
  float v = (sub < 6) ? (alpha + tE_s[sub]) : -1e30f;
  float m2 = v;
  m2 = fmaxf(m2, __shfl_xor(m2, 1));
  m2 = fmaxf(m2, __shfl_xor(m2, 2));
  m2 = fmaxf(m2, __shfl_xor(m2, 4));
  float e = (sub < 6) ? __expf(v - m2) : 0.f;
  e += __shfl_xor(e, 1); e += __shfl_xor(e, 2); e += __shfl_xor(e, 4);
  const float fwd = m2 + __logf(e);

  int fp = T_;
  for (int t = sub; t < T_; t += 8)
    if (labels[b * T_ + t] == 5) fp = min(fp, t);
  fp = min(fp, __shfl_xor(fp, 1));
  fp = min(fp, __shfl_xor(fp, 2));
  fp = min(fp, __shfl_xor(fp, 4));
  float gs = 0.f;
  for (int t = sub; t < T_; t += 8) {
    if (t < fp) {
      const int lab = labels[b * T_ + t];
      const int prv = (t == 0) ? 3 : labels[b * T_ + t - 1];
      gs += feats[(long)(b * T_ + t) * 6 + lab] + tn_s[lab * 6 + prv];
    }
  }
  gs += __shfl_xor(gs, 1); gs += __shfl_xor(gs, 2); gs += __shfl_xor(gs, 4);
  const float gold = gs + trans[4 * 6 + labels[b * T_ + T_ - 1]];
  if (sub == 0) res_s[b] = fwd - gold;
  __syncthreads();
  if (tid == 0) {
    float r = 0.f;
    for (int i = 0; i < 64; ++i) r += res_s[i];
    out[0] = r * (1.0f / 64.0f);
  }
}

// ---------------------------------------------------------------------------
extern "C" void kernel_launch(void* const* d_in, const int* in_sizes, int n_in,
                              void* d_out, int out_size, void* d_ws, size_t ws_size,
                              hipStream_t stream) {
  (void)in_sizes; (void)n_in; (void)out_size; (void)ws_size;
  const int*   words = (const int*)d_in[0];
  const int*   postg = (const int*)d_in[1];
  const int*   labels= (const int*)d_in[2];
  const float* emb_w = (const float*)d_in[3];
  const float* wlfWi = (const float*)d_in[5];
  const float* wlfWh = (const float*)d_in[6];
  const float* wlfb  = (const float*)d_in[7];
  const float* wlbWi = (const float*)d_in[8];
  const float* wlbWh = (const float*)d_in[9];
  const float* wlbb  = (const float*)d_in[10];
  const float* plfWi = (const float*)d_in[11];
  const float* plfWh = (const float*)d_in[12];
  const float* plfb  = (const float*)d_in[13];
  const float* plbWi = (const float*)d_in[14];
  const float* plbWh = (const float*)d_in[15];
  const float* plbb  = (const float*)d_in[16];
  const float* whW   = (const float*)d_in[17];
  const float* whb   = (const float*)d_in[18];
  const float* phW   = (const float*)d_in[19];
  const float* phb   = (const float*)d_in[20];
  const float* tagW  = (const float*)d_in[21];
  const float* tagb  = (const float*)d_in[22];
  const float* trans = (const float*)d_in[23];

  float* ws = (float*)d_ws;
  float* xg = ws;                          // [2][256][64][512]
  float* wo = xg + (size_t)NPOS * 1024;    // [16384][256]
  float* po = wo + (size_t)NPOS * 256;     // [16384][16]
  float* wh = po + (size_t)NPOS * 16;      // [16384][128]
  float* fe = wh + (size_t)NPOS * 128;     // [16384][6]

  hipLaunchKernelGGL(front_k, dim3(128 + 4096), dim3(256), 0, stream,
                     words, emb_w, wlfWi, wlbWi, wlfb, wlbb, xg,
                     postg, plfWi, plfWh, plfb, plbWi, plbWh, plbb, po);
  hipLaunchKernelGGL(word_lstm_mfma2, dim3(128), dim3(512), 0, stream,
                     xg, wlfWh, wlbWh, wo);
  hipLaunchKernelGGL(wh_gemm_k, dim3(NPOS / 64, 128 / 64), dim3(256), 0, stream,
                     wo, whW, whb, wh);
  hipLaunchKernelGGL(feats_k, dim3(NPOS / 256), dim3(256), 0, stream,
                     wh, po, phW, phb, tagW, tagb, fe);
  hipLaunchKernelGGL(crf_k, dim3(1), dim3(512), 0, stream,
                     words, labels, fe, trans, (float*)d_out);
}